// Round 11
// baseline (6837.742 us; speedup 1.0000x reference)
//
#include <hip/hip_runtime.h>
#include <stdint.h>

// SPINN thin-stack TreeLSTM, MI355X, round 11: fan-in 4.
// R6 anchor (1.99ms) is L2-BW-bound on the W stream (400KB/CU/step = 7.1k
// cyc of 9.6k; chip 26 TB/s ~ 77% of L2 ceiling). R11 halves the slice:
// 64 groups x 4 blocks, block owns 4 batch x 160 cols (32 h-dims) ->
// 204.8 KB/CU/step. Sync = R6's tag/record machinery generalized to 3
// partners (one tag cacheline per (t,group), u64 poll per lane + __all;
// 512B hr record per partner; cr in cell regs; li<=t-2 via watermark,
// li==t-1 piggybacked). W streamed direct (R10's LDS-W serialized).
// LDS ~85KB -> 1 blk/CU. 3 barriers/step.

#define D    512
#define HD   128
#define LD   64
#define NTHR 512

typedef unsigned long long u64t;

__device__ __forceinline__ float sigf(float x){ return 1.0f/(1.0f+__expf(-x)); }
__device__ __forceinline__ float tanh_(float x){ return 1.0f-2.0f/(__expf(2.0f*x)+1.0f); }
__device__ __forceinline__ u64t gld64(const void* p){
  return __hip_atomic_load((const u64t*)p, __ATOMIC_RELAXED, __HIP_MEMORY_SCOPE_AGENT);
}
__device__ __forceinline__ void gst32(float* p, float v){
  __hip_atomic_store(p, v, __ATOMIC_RELAXED, __HIP_MEMORY_SCOPE_AGENT);
}
__device__ __forceinline__ void gsttag(unsigned* p, unsigned v){
  __hip_atomic_store(p, v, __ATOMIC_RELAXED, __HIP_MEMORY_SCOPE_AGENT);
}

__global__ __launch_bounds__(NTHR,1) void spinn_kernel(
    const int* __restrict__ trans, const int* __restrict__ labels,
    const float* __restrict__ emb, const float* __restrict__ W,
    const float* __restrict__ bias, const float* __restrict__ leaf,
    float* __restrict__ out, unsigned* __restrict__ tags,
    float* __restrict__ hP, float* __restrict__ cP)
{
  const int bid = blockIdx.x;
  const int g4 = bid>>2, sl = bid&3;       // 64 groups x 4 slots
  const int gb0 = g4*4;                    // 4 batch elems per group
  const int tid = threadIdx.x;
  const int kg = tid>>6, lane = tid&63;
  const int bq = lane>>5, q = lane&31;     // batch-half, col-slot
  const int qg = q>>3, qo = q&7;           // gate (0..3), quad-in-gate

  __shared__ __align__(16) float xs[2][4][324];   // [buf][b][k] (+4 pad)
  __shared__ __align__(16) float gpq[8][4][164];  // K-partials [kg][b][col]
  __shared__ float bsl[160];
  __shared__ float lshd[HD];
  __shared__ float clb[2][4][32];
  __shared__ uint8_t mS[D][4];
  __shared__ short liA[D][4];
  __shared__ unsigned short stk_[4][D];
  __shared__ float padL[10240];   // pad LDS ~85KB: force 1 block/CU

  const int gqcol = qg*128 + sl*32 + qo*4;  // quad base col (gates i,fl,fr,o)
  const int gucol = 512 + sl*32 + q;        // u-gate col

  if (tid < 160){
    int c = tid;
    bsl[c] = (c < 128) ? bias[(c>>5)*128 + sl*32 + (c&31)]
                       : bias[512 + sl*32 + (c-128)];
  }
  if (tid < HD) lshd[tid] = leaf[tid];
  if (tid < 4){   // precompute (mask, li); ri == t-1 always on a reduce
    int b = tid, p = 0;
    for (int t=0;t<D;++t){
      int m = trans[t*256 + gb0 + b];
      short li = 0;
      if (m) li = (short)stk_[b][p-2];
      mS[t][b] = (uint8_t)m; liA[t][b] = li;
      int np = p - 2*m; stk_[b][np] = (unsigned short)t; p = np+1;
    }
  }
  __syncthreads();

  padL[(tid*29)&10239] = lshd[tid&127];

  // prefill xs[0]: emb(labels[0]) + leaf (mask==0 at t=0 by construction)
  for (int idx = tid; idx < 4*320; idx += NTHR){
    int b = idx / 320, r = idx - b*320;
    xs[0][b][r] = (r < 64) ? emb[(size_t)labels[gb0+b]*LD + r]
                           : lshd[(r-64)&127];
  }
  __syncthreads();
  if (padL[(tid*31)&10239] == 3.25e18f) xs[0][0][0] += 1.f;  // keep pad alive

  auto gemm = [&](int cur){
    float4 a0 = {0.f,0.f,0.f,0.f}, a1 = {0.f,0.f,0.f,0.f};
    float u0 = 0.f, u1 = 0.f;
    const int b0 = bq*2, b1 = bq*2+1;
#pragma unroll
    for (int j4=0;j4<10;++j4){
      int k = kg*40 + j4*4;
      float4 x0 = *(const float4*)&xs[cur][b0][k];   // 2-addr broadcast
      float4 x1 = *(const float4*)&xs[cur][b1][k];
      float xa0[4]={x0.x,x0.y,x0.z,x0.w}, xa1[4]={x1.x,x1.y,x1.z,x1.w};
#pragma unroll
      for (int jj=0;jj<4;++jj){
        int kk = k + jj;
        float4 w = *(const float4*)(W + (size_t)kk*640 + gqcol);
        float wu = W[(size_t)kk*640 + gucol];
        a0.x=__builtin_fmaf(w.x,xa0[jj],a0.x); a0.y=__builtin_fmaf(w.y,xa0[jj],a0.y);
        a0.z=__builtin_fmaf(w.z,xa0[jj],a0.z); a0.w=__builtin_fmaf(w.w,xa0[jj],a0.w);
        a1.x=__builtin_fmaf(w.x,xa1[jj],a1.x); a1.y=__builtin_fmaf(w.y,xa1[jj],a1.y);
        a1.z=__builtin_fmaf(w.z,xa1[jj],a1.z); a1.w=__builtin_fmaf(w.w,xa1[jj],a1.w);
        u0=__builtin_fmaf(wu,xa0[jj],u0);      u1=__builtin_fmaf(wu,xa1[jj],u1);
      }
    }
    *(float4*)&gpq[kg][b0][qg*32+qo*4] = a0;
    *(float4*)&gpq[kg][b1][qg*32+qo*4] = a1;
    gpq[kg][b0][128+q] = u0;
    gpq[kg][b1][128+q] = u1;
  };

  float ccprev = 0.f;   // own c[t-1][b][dl] (cell threads only)

  for (int t=0;t<D;++t){
    const int cur = t&1, nxt = cur^1;

    // ---- P1: GEMM K<160 (waves 0-3) || prefetch (4-6) || hr spin (7) ----
    if (kg < 4){
      gemm(cur);
    } else if (kg == 4){          // emb for t+1
      if (t+1 < D){
        int b = lane>>4, seg = lane&15;
        int row = labels[(t+1)*256 + gb0 + b];
        float4 ev = *(const float4*)(emb + (size_t)row*LD + seg*4);
        *(float4*)&xs[nxt][b][seg*4] = ev;
      }
    } else if (kg == 5){          // own-dims hl/cl for t+1
      if (t+1 < D){
        int b = lane>>4, d2 = (lane&15)*2;
        if (mS[t+1][b]){
          int li = liA[t+1][b];
          if (li <= t-2){
            size_t po = (((size_t)li*64+g4)*4 + sl)*128 + b*32 + d2;
            union{u64t u; float f[2];} h_, c_;
            h_.u = gld64(hP + po); c_.u = gld64(cP + po);
            xs[nxt][b][64+sl*32+d2]   = h_.f[0];
            xs[nxt][b][64+sl*32+d2+1] = h_.f[1];
            clb[nxt][b][d2] = c_.f[0]; clb[nxt][b][d2+1] = c_.f[1];
          }
          // li == t-1: cell@t-1 wrote xs/clb from registers
        } else {
          xs[nxt][b][64+sl*32+d2]   = lshd[sl*32+d2];
          xs[nxt][b][64+sl*32+d2+1] = lshd[sl*32+d2+1];
          clb[nxt][b][d2] = lshd[sl*32+d2]; clb[nxt][b][d2+1] = lshd[sl*32+d2+1];
        }
      }
    } else if (kg == 6){          // partner-dims hl for t+1 (3 u64/lane)
      if (t+1 < D){
#pragma unroll
        for (int r=0;r<3;++r){
          int idx = r*64 + lane;
          int p = idx>>6, w = idx&63, b = w>>4, d2 = (w&15)*2;
          int psl = p + (p >= sl);
          if (mS[t+1][b]){
            int li = liA[t+1][b];
            if (li <= t-2){
              size_t po = (((size_t)li*64+g4)*4 + psl)*128 + b*32 + d2;
              union{u64t u; float f[2];} h_; h_.u = gld64(hP + po);
              xs[nxt][b][64+psl*32+d2]   = h_.f[0];
              xs[nxt][b][64+psl*32+d2+1] = h_.f[1];
            }
            // li == t-1: wave 7 piggybacks from the hr record this step
          } else {
            xs[nxt][b][64+psl*32+d2]    = lshd[psl*32+d2];
            xs[nxt][b][64+psl*32+d2+1]  = lshd[psl*32+d2+1];
            xs[nxt][b][192+psl*32+d2]   = lshd[psl*32+d2];
            xs[nxt][b][192+psl*32+d2+1] = lshd[psl*32+d2+1];
          }
        }
      }
    } else {                      // kg == 7: spin + partner hr (t-1)
      if (t > 0){
        const unsigned* tline = tags + ((size_t)(t-1)*64 + g4)*16;
        const u64t want = ((u64t)(unsigned)(t-1) << 32) | (unsigned)(t-1);
        bool mine = (lane < 4) && (lane != sl);
        const u64t* tp = (const u64t*)tline + lane;
        u64t v = mine ? gld64(tp) : want;
        int it = 0;
        while (!__all((v == want) ? 1 : 0)){
          if (++it > (1<<20)) break;   // safety: hang -> wrong answer
          __builtin_amdgcn_s_sleep(1);
          if (mine && v != want) v = gld64(tp);
        }
#pragma unroll
        for (int r=0;r<3;++r){
          int idx = r*64 + lane;
          int p = idx>>6, w = idx&63, b = w>>4, d2 = (w&15)*2;
          int psl = p + (p >= sl);
          bool needR = (mS[t][b] != 0);
          bool needL = (t+1 < D) && mS[t+1][b] && (liA[t+1][b] == t-1);
          if (needR || needL){
            size_t po = (((size_t)(t-1)*64+g4)*4 + psl)*128 + b*32 + d2;
            union{u64t u; float f[2];} h_; h_.u = gld64(hP + po);
            if (needR){
              xs[cur][b][192+psl*32+d2]   = h_.f[0];
              xs[cur][b][192+psl*32+d2+1] = h_.f[1];
            }
            if (needL){
              xs[nxt][b][64+psl*32+d2]   = h_.f[0];
              xs[nxt][b][64+psl*32+d2+1] = h_.f[1];
            }
          }
        }
      }
    }
    __syncthreads();

    // ---- P2: GEMM K in [160,320) (waves 4-7) ----
    if (kg >= 4){ gemm(cur); }
    __syncthreads();

    // ---- P3: cell (2 waves: 4 batch x 32 dims) ----
    if (tid < 128){
      const int b = tid>>5, dl = tid&31, gd = sl*32+dl;
      const int m = mS[t][b];
      float s0=0.f,s1=0.f,s2=0.f,s3=0.f,s4=0.f;
#pragma unroll
      for (int kk=0;kk<8;++kk){
        const float* gr = gpq[kk][b];
        s0 += gr[dl]; s1 += gr[32+dl]; s2 += gr[64+dl];
        s3 += gr[96+dl]; s4 += gr[128+dl];
      }
      s0 += bsl[dl]; s1 += bsl[32+dl]; s2 += bsl[64+dl];
      s3 += bsl[96+dl]; s4 += bsl[128+dl];
      float cl_ = m ? clb[cur][b][dl] : lshd[gd];
      float cr_ = m ? ccprev : lshd[gd];       // ri == t-1: own prev c
      float cc = sigf(s0)*tanh_(s4) + sigf(s1)*cl_ + sigf(s2)*cr_;
      float hh = sigf(s3)*tanh_(cc);
      ccprev = cc;
      size_t po = (((size_t)t*64+g4)*4 + sl)*128 + b*32 + dl;
      gst32(hP + po, hh);
      gst32(cP + po, cc);
      if (t == D-1){
        out[(size_t)(gb0+b)*HD + gd] = cc;
        out[(size_t)256*HD + (size_t)(gb0+b)*HD + gd] = hh;
      } else {
        xs[nxt][b][192+sl*32+dl] = mS[t+1][b] ? hh : lshd[gd];  // own hr
      }
      if (t+2 < D && mS[t+2][b] && liA[t+2][b] == t){
        xs[cur][b][64+sl*32+dl] = hh;    // own hl for t+2 (li==t case)
        clb[cur][b][dl]         = cc;    // own cl for t+2
      }
      __asm__ volatile("s_waitcnt vmcnt(0)" ::: "memory");  // wave drain
      if ((tid & 63) == 0){
        int w = tid>>6;
        gsttag(tags + ((size_t)t*64 + g4)*16 + sl*2 + w, (unsigned)t);
      }
    }
    __syncthreads();
  }
}

extern "C" void kernel_launch(void* const* d_in, const int* in_sizes, int n_in,
                              void* d_out, int out_size, void* d_ws, size_t ws_size,
                              hipStream_t stream) {
  (void)in_sizes; (void)n_in; (void)out_size; (void)ws_size;
  const int*   trans  = (const int*)d_in[0];
  const int*   labels = (const int*)d_in[1];
  const float* emb    = (const float*)d_in[2];
  const float* W      = (const float*)d_in[3];
  const float* bias   = (const float*)d_in[4];
  const float* leaf   = (const float*)d_in[5];
  float* out = (float*)d_out;

  // ws: [0,2MiB) tags: 64B line per (t,g4), 8 u32 = 4 slots x 2 waves
  //     (0xAA poison != any t<512 -> no init dispatch)
  //     [2,66) MiB hP | [66,130) MiB cP: 128 f32 per (t,g4,sl)
  uint8_t* ws = (uint8_t*)d_ws;
  unsigned* tags = (unsigned*)ws;
  float* hP = (float*)(ws + ((size_t)2<<20));
  float* cP = (float*)(ws + ((size_t)66<<20));

  spinn_kernel<<<dim3(256), dim3(NTHR), 0, stream>>>(
      trans, labels, emb, W, bias, leaf, out, tags, hP, cP);
}